// Round 1
// baseline (1186.882 us; speedup 1.0000x reference)
//
#include <hip/hip_runtime.h>
#include <cstdint>
#include <cstddef>

// Problem constants: B=64, TQ=64, TP=1024, H=A=1024
typedef unsigned short u16;
typedef __bf16 bf16x8 __attribute__((ext_vector_type(8)));
typedef float floatx4 __attribute__((ext_vector_type(4)));

__device__ __forceinline__ u16 f32_to_bf16(float f) {
    unsigned u = __builtin_bit_cast(unsigned, f);
    u += 0x7fffu + ((u >> 16) & 1u);   // round-to-nearest-even
    return (u16)(u >> 16);
}
__device__ __forceinline__ float bf16_lo(unsigned u) {
    return __builtin_bit_cast(float, u << 16);
}
__device__ __forceinline__ float bf16_hi(unsigned u) {
    return __builtin_bit_cast(float, u & 0xffff0000u);
}
__device__ __forceinline__ float fast_tanh(float x) {
    // tanh(x) = 1 - 2/(1+e^{2x}); saturates correctly at +/-inf
    float e = __expf(2.0f * x);
    return 1.0f - 2.0f * __builtin_amdgcn_rcpf(e + 1.0f);
}
__device__ __forceinline__ float fast_sigmoid(float x) {
    return __builtin_amdgcn_rcpf(1.0f + __expf(-x));
}

// ---------------------------------------------------------------------------
// Transpose+convert: W fp32 [K,N] -> WT bf16 [N,K]
// ---------------------------------------------------------------------------
__global__ __launch_bounds__(256) void transpose_bf16_kernel(
    const float* __restrict__ W, u16* __restrict__ WT, int K, int N)
{
    __shared__ float tile[32][33];
    const int k0 = blockIdx.y * 32, n0 = blockIdx.x * 32;
    const int tid = threadIdx.x;
#pragma unroll
    for (int i = 0; i < 4; ++i) {
        int e = tid + i * 256, rr = e >> 5, cc = e & 31;
        tile[rr][cc] = W[(size_t)(k0 + rr) * N + (n0 + cc)];
    }
    __syncthreads();
#pragma unroll
    for (int i = 0; i < 4; ++i) {
        int e = tid + i * 256, rr = e >> 5, cc = e & 31;   // rr: n-in-tile, cc: k-in-tile
        WT[(size_t)(n0 + rr) * K + (k0 + cc)] = f32_to_bf16(tile[cc][rr]);
    }
}

// ---------------------------------------------------------------------------
// vWq[a] = sum_h V_q[h] * Wq_q[h,a]    (A = 1024)
// ---------------------------------------------------------------------------
__global__ __launch_bounds__(256) void vq_proj_kernel(
    const float* __restrict__ Vq, const float* __restrict__ Wq, float* __restrict__ out)
{
    const int a = blockIdx.x * 256 + threadIdx.x;
    float acc = 0.f;
#pragma unroll 8
    for (int h = 0; h < 1024; ++h)
        acc += Vq[h] * Wq[(size_t)h * 1024 + a];
    out[a] = acc;
}

// ---------------------------------------------------------------------------
// Big GEMM: C[M,N] bf16 = (A fp32 [M,K] cast->bf16) @ (BT bf16 [N,K])^T
// 128x128 tile, BK=32, 4 waves (2x2), 16x16x32 bf16 MFMA, 4x4 frags/wave.
// A is converted fp32->bf16 in registers during LDS staging.
// ---------------------------------------------------------------------------
__global__ __launch_bounds__(256) void gemm_conv_kernel(
    const float* __restrict__ A, const u16* __restrict__ BT,
    u16* __restrict__ C, int M, int K, int N)
{
    __shared__ __align__(16) u16 As[128][32];   // 8 KB  [m][k]
    __shared__ __align__(16) u16 Bs[128][32];   // 8 KB  [n][k]
    const int tid  = threadIdx.x;
    const int lane = tid & 63;
    const int wave = tid >> 6;
    const int wm = (wave >> 1) * 64, wn = (wave & 1) * 64;
    const int quad = lane >> 4, lr = lane & 15;
    const int m0 = blockIdx.y * 128;
    const int n0 = blockIdx.x * 128;

    floatx4 acc[4][4] = {};

    for (int k0 = 0; k0 < K; k0 += 32) {
        // Stage A: 128x32 fp32 -> bf16.  4 float4 per thread.
#pragma unroll
        for (int i = 0; i < 4; ++i) {
            int f = tid + i * 256;            // float4 chunk 0..1023
            int row = f >> 3, c4 = f & 7;
            float4 v = *(const float4*)(A + (size_t)(m0 + row) * K + (k0 + c4 * 4));
            ushort4 hq;
            hq.x = f32_to_bf16(v.x); hq.y = f32_to_bf16(v.y);
            hq.z = f32_to_bf16(v.z); hq.w = f32_to_bf16(v.w);
            *(ushort4*)(&As[row][c4 * 4]) = hq;
        }
        // Stage B: 128x32 bf16, 2 x 16B per thread.
#pragma unroll
        for (int i = 0; i < 2; ++i) {
            int c = tid + i * 256;            // 16B chunk 0..511
            int n = c >> 2, part = c & 3;
            uint4 v = *(const uint4*)(BT + (size_t)(n0 + n) * K + (k0 + part * 8));
            *(uint4*)(&Bs[n][part * 8]) = v;
        }
        __syncthreads();
        bf16x8 af[4], bfr[4];
#pragma unroll
        for (int i = 0; i < 4; ++i)
            af[i] = *(const bf16x8*)(&As[wm + i * 16 + lr][quad * 8]);
#pragma unroll
        for (int j = 0; j < 4; ++j)
            bfr[j] = *(const bf16x8*)(&Bs[wn + j * 16 + lr][quad * 8]);
#pragma unroll
        for (int i = 0; i < 4; ++i)
#pragma unroll
            for (int j = 0; j < 4; ++j)
                acc[i][j] = __builtin_amdgcn_mfma_f32_16x16x32_bf16(af[i], bfr[j], acc[i][j], 0, 0, 0);
        __syncthreads();
    }
    // Epilogue: C/D layout col = lane&15, row = quad*4 + reg
#pragma unroll
    for (int i = 0; i < 4; ++i) {
        int rb = m0 + wm + i * 16 + quad * 4;
#pragma unroll
        for (int j = 0; j < 4; ++j) {
            int col = n0 + wn + j * 16 + lr;
#pragma unroll
            for (int rg = 0; rg < 4; ++rg)
                C[(size_t)(rb + rg) * N + col] = f32_to_bf16(acc[i][j][rg]);
        }
    }
}

// ---------------------------------------------------------------------------
// s[row] = mask ? sum_a tanh(R[row,a] + shift[row/shiftDiv, a]) * wv[a] : -1e30
// One wave per row; R is bf16 [rows,1024].
// ---------------------------------------------------------------------------
__global__ __launch_bounds__(256) void tanh_dot_kernel(
    const u16* __restrict__ R, const float* __restrict__ shift,
    const float* __restrict__ wv, const float* __restrict__ mask,
    float* __restrict__ out, int shiftDiv)
{
    const int row  = blockIdx.x * 4 + (threadIdx.x >> 6);
    const int lane = threadIdx.x & 63;
    const u16* rp   = R + (size_t)row * 1024;
    const float* sp = shift + (size_t)(row / shiftDiv) * 1024;
    float acc = 0.f;
#pragma unroll
    for (int p = 0; p < 2; ++p) {
        const int a0 = (p * 64 + lane) * 8;
        uint4  rv = *(const uint4*)(rp + a0);
        float4 s0 = *(const float4*)(sp + a0);
        float4 s1 = *(const float4*)(sp + a0 + 4);
        float4 w0 = *(const float4*)(wv + a0);
        float4 w1 = *(const float4*)(wv + a0 + 4);
        acc += fast_tanh(bf16_lo(rv.x) + s0.x) * w0.x;
        acc += fast_tanh(bf16_hi(rv.x) + s0.y) * w0.y;
        acc += fast_tanh(bf16_lo(rv.y) + s0.z) * w0.z;
        acc += fast_tanh(bf16_hi(rv.y) + s0.w) * w0.w;
        acc += fast_tanh(bf16_lo(rv.z) + s1.x) * w1.x;
        acc += fast_tanh(bf16_hi(rv.z) + s1.y) * w1.y;
        acc += fast_tanh(bf16_lo(rv.w) + s1.z) * w1.z;
        acc += fast_tanh(bf16_hi(rv.w) + s1.w) * w1.w;
    }
#pragma unroll
    for (int off = 32; off > 0; off >>= 1)
        acc += __shfl_down(acc, off, 64);
    if (lane == 0)
        out[row] = (mask[row] > 0.f) ? acc : -1e30f;
}

// ---------------------------------------------------------------------------
// Question pool: softmax over TQ=64 then hidden[b,h] = sum_t alpha[t]*q[b,t,h]
// ---------------------------------------------------------------------------
__global__ __launch_bounds__(256) void pool_q_kernel(
    const float* __restrict__ s, const float* __restrict__ seq, float* __restrict__ hidden)
{
    const int b = blockIdx.x, tid = threadIdx.x;
    __shared__ float alpha[64];
    if (tid < 64) {
        float v = s[b * 64 + tid];
        float m = v;
#pragma unroll
        for (int off = 32; off > 0; off >>= 1) m = fmaxf(m, __shfl_xor(m, off, 64));
        float e = __expf(v - m);
        float sum = e;
#pragma unroll
        for (int off = 32; off > 0; off >>= 1) sum += __shfl_xor(sum, off, 64);
        alpha[tid] = e * __builtin_amdgcn_rcpf(sum);
    }
    __syncthreads();
    float acc[4] = {0.f, 0.f, 0.f, 0.f};
    const float* base = seq + (size_t)b * 64 * 1024;
    for (int t = 0; t < 64; ++t) {
        const float a = alpha[t];
#pragma unroll
        for (int j = 0; j < 4; ++j)
            acc[j] += a * base[(size_t)t * 1024 + tid + j * 256];
    }
#pragma unroll
    for (int j = 0; j < 4; ++j) hidden[b * 1024 + tid + j * 256] = acc[j];
}

// ---------------------------------------------------------------------------
// Passage pool: softmax over TP=1024, pooled[b,h] = sum_t alpha[t]*p[b,t,h]
// ---------------------------------------------------------------------------
__global__ __launch_bounds__(256) void pool_p_kernel(
    const float* __restrict__ s, const float* __restrict__ seq, float* __restrict__ pooled)
{
    const int b = blockIdx.x, tid = threadIdx.x;
    const int lane = tid & 63, wid = tid >> 6;
    __shared__ float alpha[1024];
    __shared__ float redm[4], reds[4];
    const float* sr = s + b * 1024;
    float v[4];
    float m = -3.4e38f;
#pragma unroll
    for (int j = 0; j < 4; ++j) { v[j] = sr[tid + j * 256]; m = fmaxf(m, v[j]); }
#pragma unroll
    for (int off = 32; off > 0; off >>= 1) m = fmaxf(m, __shfl_xor(m, off, 64));
    if (lane == 0) redm[wid] = m;
    __syncthreads();
    m = fmaxf(fmaxf(redm[0], redm[1]), fmaxf(redm[2], redm[3]));
    float sum = 0.f;
#pragma unroll
    for (int j = 0; j < 4; ++j) { float e = __expf(v[j] - m); alpha[tid + j * 256] = e; sum += e; }
#pragma unroll
    for (int off = 32; off > 0; off >>= 1) sum += __shfl_xor(sum, off, 64);
    if (lane == 0) reds[wid] = sum;
    __syncthreads();
    const float rs = __builtin_amdgcn_rcpf(reds[0] + reds[1] + reds[2] + reds[3]);
#pragma unroll
    for (int j = 0; j < 4; ++j) alpha[tid + j * 256] *= rs;
    __syncthreads();
    float acc[4] = {0.f, 0.f, 0.f, 0.f};
    const float* base = seq + (size_t)b * (1024 * 1024);
    for (int t = 0; t < 1024; ++t) {
        const float a = alpha[t];
#pragma unroll
        for (int j = 0; j < 4; ++j)
            acc[j] += a * base[(size_t)t * 1024 + tid + j * 256];
    }
#pragma unroll
    for (int j = 0; j < 4; ++j) pooled[b * 1024 + tid + j * 256] = acc[j];
}

// ---------------------------------------------------------------------------
// Small fp32 GEMM: out[64,N] = X[64,K] @ B  (B is [N,K] if BT else [K,N])
// 64x64 tile per block, BK=16, 4x4 micro-tile. blockIdx.y picks operand set.
// ---------------------------------------------------------------------------
template <bool BT>
__global__ __launch_bounds__(256) void small_gemm_kernel(
    const float* __restrict__ X0, const float* __restrict__ X1,
    const float* __restrict__ B0, const float* __restrict__ B1,
    float* __restrict__ out0, float* __restrict__ out1, int K, int N)
{
    const float* X  = blockIdx.y ? X1 : X0;
    const float* Bm = blockIdx.y ? B1 : B0;
    float* out      = blockIdx.y ? out1 : out0;
    const int n0 = blockIdx.x * 64;
    const int tid = threadIdx.x, tx = tid & 15, ty = tid >> 4;
    __shared__ float Xs[64][17];
    __shared__ float Bs[64][17];
    float acc[4][4] = {};
    for (int kc = 0; kc < K; kc += 16) {
        {
            int e = tid * 4, row = e >> 4, kk = e & 15;
            float4 v = *(const float4*)(X + (size_t)row * K + kc + kk);
            Xs[row][kk] = v.x; Xs[row][kk + 1] = v.y; Xs[row][kk + 2] = v.z; Xs[row][kk + 3] = v.w;
        }
        if (BT) {
            int e = tid * 4, n = e >> 4, kk = e & 15;
            float4 v = *(const float4*)(Bm + (size_t)(n0 + n) * K + kc + kk);
            Bs[n][kk] = v.x; Bs[n][kk + 1] = v.y; Bs[n][kk + 2] = v.z; Bs[n][kk + 3] = v.w;
        } else {
            int c = tid & 63, kb = tid >> 6;
#pragma unroll
            for (int u = 0; u < 4; ++u) {
                int k = kb + u * 4;
                Bs[c][k] = Bm[(size_t)(kc + k) * N + n0 + c];
            }
        }
        __syncthreads();
#pragma unroll
        for (int k = 0; k < 16; ++k) {
            float xr[4], br[4];
#pragma unroll
            for (int bi = 0; bi < 4; ++bi) xr[bi] = Xs[ty * 4 + bi][k];
#pragma unroll
            for (int ni = 0; ni < 4; ++ni) br[ni] = Bs[tx * 4 + ni][k];
#pragma unroll
            for (int bi = 0; bi < 4; ++bi)
#pragma unroll
                for (int ni = 0; ni < 4; ++ni)
                    acc[bi][ni] += xr[bi] * br[ni];
        }
        __syncthreads();
    }
#pragma unroll
    for (int bi = 0; bi < 4; ++bi)
#pragma unroll
        for (int ni = 0; ni < 4; ++ni)
            out[(size_t)(ty * 4 + bi) * N + n0 + tx * 4 + ni] = acc[bi][ni];
}

// ---------------------------------------------------------------------------
// GRU cell combine (torch.nn.GRUCell math), biases applied here.
// ---------------------------------------------------------------------------
__global__ __launch_bounds__(256) void gru_combine_kernel(
    const float* __restrict__ gi, const float* __restrict__ gh,
    const float* __restrict__ bih, const float* __restrict__ bhh,
    const float* __restrict__ h, float* __restrict__ out)
{
    const int idx = blockIdx.x * 256 + threadIdx.x;   // 0..65535
    const int b = idx >> 10, j = idx & 1023;
    const float* gib = gi + (size_t)b * 3072;
    const float* ghb = gh + (size_t)b * 3072;
    float ir = gib[j] + bih[j],               hr = ghb[j] + bhh[j];
    float iz = gib[1024 + j] + bih[1024 + j], hz = ghb[1024 + j] + bhh[1024 + j];
    float in_ = gib[2048 + j] + bih[2048 + j], hn = ghb[2048 + j] + bhh[2048 + j];
    float r = fast_sigmoid(ir + hr);
    float z = fast_sigmoid(iz + hz);
    float n = fast_tanh(in_ + r * hn);
    out[idx] = (1.f - z) * n + z * h[idx];
}

// ---------------------------------------------------------------------------
extern "C" void kernel_launch(void* const* d_in, const int* in_sizes, int n_in,
                              void* d_out, int out_size, void* d_ws, size_t ws_size,
                              hipStream_t stream)
{
    const float* question      = (const float*)d_in[0];   // [64,64,1024]
    const float* question_mask = (const float*)d_in[1];   // [64,64]
    const float* passage       = (const float*)d_in[2];   // [64,1024,1024]
    const float* passage_mask  = (const float*)d_in[3];   // [64,1024]
    const float* V_q  = (const float*)d_in[4];            // [1024]
    const float* Wk_q = (const float*)d_in[5];            // [1024,1024]
    const float* Wq_q = (const float*)d_in[6];
    const float* w_q  = (const float*)d_in[7];
    const float* Wk_p = (const float*)d_in[8];
    const float* Wq_p = (const float*)d_in[9];
    const float* w_p  = (const float*)d_in[10];
    const float* W_ih = (const float*)d_in[11];           // [3072,1024]
    const float* W_hh = (const float*)d_in[12];
    const float* b_ih = (const float*)d_in[13];
    const float* b_hh = (const float*)d_in[14];

    char* ws = (char*)d_ws;
    auto alloc = [&](size_t bytes) { char* p = ws; ws += (bytes + 255) & ~(size_t)255; return p; };
    u16* WkQT = (u16*)alloc((size_t)1024 * 1024 * 2);     // Wk_q^T bf16 [A,K]
    u16* WkPT = (u16*)alloc((size_t)1024 * 1024 * 2);     // Wk_p^T bf16 [A,K]
    u16* qWk  = (u16*)alloc((size_t)4096 * 1024 * 2);     // question@Wk_q bf16
    u16* pWk  = (u16*)alloc((size_t)65536 * 1024 * 2);    // passage@Wk_p bf16 (128 MB)
    float* vWq    = (float*)alloc(1024 * 4);
    float* s_q    = (float*)alloc(4096 * 4);
    float* hidden = (float*)alloc(65536 * 4);
    float* hWq    = (float*)alloc(65536 * 4);
    float* pooled = (float*)alloc(65536 * 4);
    float* gi     = (float*)alloc((size_t)64 * 3072 * 4);
    float* gh     = (float*)alloc((size_t)64 * 3072 * 4);
    float* gout   = (float*)alloc(65536 * 4);
    float* oWq    = (float*)alloc(65536 * 4);

    float* ans_begin = (float*)d_out;          // [64,1024]
    float* ans_end   = ans_begin + 65536;      // [64,1024]

    // weight prep
    transpose_bf16_kernel<<<dim3(32, 32), 256, 0, stream>>>(Wk_q, WkQT, 1024, 1024);
    transpose_bf16_kernel<<<dim3(32, 32), 256, 0, stream>>>(Wk_p, WkPT, 1024, 1024);

    // big GEMM first (dominant): pWk = passage @ Wk_p  (bf16 out)
    gemm_conv_kernel<<<dim3(8, 512), 256, 0, stream>>>(passage, WkPT, pWk, 65536, 1024, 1024);

    // question path
    gemm_conv_kernel<<<dim3(8, 32), 256, 0, stream>>>(question, WkQT, qWk, 4096, 1024, 1024);
    vq_proj_kernel<<<dim3(4), 256, 0, stream>>>(V_q, Wq_q, vWq);
    tanh_dot_kernel<<<dim3(1024), 256, 0, stream>>>(qWk, vWq, w_q, question_mask, s_q, 4096);
    pool_q_kernel<<<dim3(64), 256, 0, stream>>>(s_q, question, hidden);

    // begin logits
    small_gemm_kernel<false><<<dim3(16, 1), 256, 0, stream>>>(hidden, hidden, Wq_p, Wq_p, hWq, hWq, 1024, 1024);
    tanh_dot_kernel<<<dim3(16384), 256, 0, stream>>>(pWk, hWq, w_p, passage_mask, ans_begin, 1024);

    // passage pool + GRU step
    pool_p_kernel<<<dim3(64), 256, 0, stream>>>(ans_begin, passage, pooled);
    small_gemm_kernel<true><<<dim3(48, 2), 256, 0, stream>>>(pooled, hidden, W_ih, W_hh, gi, gh, 1024, 3072);
    gru_combine_kernel<<<dim3(256), 256, 0, stream>>>(gi, gh, b_ih, b_hh, hidden, gout);

    // end logits
    small_gemm_kernel<false><<<dim3(16, 1), 256, 0, stream>>>(gout, gout, Wq_p, Wq_p, oWq, oWq, 1024, 1024);
    tanh_dot_kernel<<<dim3(16384), 256, 0, stream>>>(pWk, oWq, w_p, passage_mask, ans_end, 1024);
}

// Round 2
// 990.761 us; speedup vs baseline: 1.1979x; 1.1979x over previous
//
#include <hip/hip_runtime.h>
#include <cstdint>
#include <cstddef>

// Problem constants: B=64, TQ=64, TP=1024, H=A=1024
typedef unsigned short u16;
typedef __bf16 bf16x8 __attribute__((ext_vector_type(8)));
typedef float floatx4 __attribute__((ext_vector_type(4)));

__device__ __forceinline__ u16 f32_to_bf16(float f) {
    unsigned u = __builtin_bit_cast(unsigned, f);
    u += 0x7fffu + ((u >> 16) & 1u);   // round-to-nearest-even
    return (u16)(u >> 16);
}
__device__ __forceinline__ unsigned pack_bf16x2(float lo, float hi) {
    return (unsigned)f32_to_bf16(lo) | ((unsigned)f32_to_bf16(hi) << 16);
}
__device__ __forceinline__ float bf16_lo(unsigned u) {
    return __builtin_bit_cast(float, u << 16);
}
__device__ __forceinline__ float bf16_hi(unsigned u) {
    return __builtin_bit_cast(float, u & 0xffff0000u);
}
__device__ __forceinline__ float fast_tanh(float x) {
    float e = __expf(2.0f * x);
    return 1.0f - 2.0f * __builtin_amdgcn_rcpf(e + 1.0f);
}
__device__ __forceinline__ float fast_sigmoid(float x) {
    return __builtin_amdgcn_rcpf(1.0f + __expf(-x));
}
// async global->LDS, 16 B per lane. LDS dest is wave-uniform base + lane*16.
__device__ __forceinline__ void async_copy16(void* lds, const void* g) {
    __builtin_amdgcn_global_load_lds((const __attribute__((address_space(1))) void*)g,
                                     (__attribute__((address_space(3))) void*)lds,
                                     16, 0, 0);
}

// ---------------------------------------------------------------------------
// fp32 -> bf16 bulk convert. Each thread: 8 floats -> one 16B store.
// ---------------------------------------------------------------------------
__global__ __launch_bounds__(256) void conv_bf16_kernel(
    const float* __restrict__ in, u16* __restrict__ out)
{
    const size_t i = ((size_t)blockIdx.x * 256 + threadIdx.x) * 8;
    float4 a = *(const float4*)(in + i);
    float4 b = *(const float4*)(in + i + 4);
    uint4 o;
    o.x = pack_bf16x2(a.x, a.y);
    o.y = pack_bf16x2(a.z, a.w);
    o.z = pack_bf16x2(b.x, b.y);
    o.w = pack_bf16x2(b.z, b.w);
    *(uint4*)(out + i) = o;
}

// ---------------------------------------------------------------------------
// Transpose+convert: W fp32 [K,N] -> WT bf16 [N,K]
// ---------------------------------------------------------------------------
__global__ __launch_bounds__(256) void transpose_bf16_kernel(
    const float* __restrict__ W, u16* __restrict__ WT, int K, int N)
{
    __shared__ float tile[32][33];
    const int k0 = blockIdx.y * 32, n0 = blockIdx.x * 32;
    const int tid = threadIdx.x;
#pragma unroll
    for (int i = 0; i < 4; ++i) {
        int e = tid + i * 256, rr = e >> 5, cc = e & 31;
        tile[rr][cc] = W[(size_t)(k0 + rr) * N + (n0 + cc)];
    }
    __syncthreads();
#pragma unroll
    for (int i = 0; i < 4; ++i) {
        int e = tid + i * 256, rr = e >> 5, cc = e & 31;
        WT[(size_t)(n0 + rr) * K + (k0 + cc)] = f32_to_bf16(tile[cc][rr]);
    }
}

// ---------------------------------------------------------------------------
// vWq[a] += sum_{h in chunk} V_q[h] * Wq_q[h,a].  grid (4, 8), atomicAdd.
// ---------------------------------------------------------------------------
__global__ __launch_bounds__(256) void vq_proj_kernel(
    const float* __restrict__ Vq, const float* __restrict__ Wq, float* __restrict__ out)
{
    const int a = blockIdx.x * 256 + threadIdx.x;
    const int h0 = blockIdx.y * 128;
    float acc = 0.f;
#pragma unroll 8
    for (int h = h0; h < h0 + 128; ++h)
        acc += Vq[h] * Wq[(size_t)h * 1024 + a];
    atomicAdd(&out[a], acc);
}

// ---------------------------------------------------------------------------
// m97-structure GEMM: C[M,N] bf16 = A bf16 [M,K] @ (BT bf16 [N,K])^T
// 128x128 tile, BK=32, 4 waves (2x2), 16x16x32 bf16 MFMA, 4x4 frags/wave.
// Staging via global_load_lds dwordx4 (16B/lane).
// ---------------------------------------------------------------------------
__global__ __launch_bounds__(256) void gemm_bf16_kernel(
    const u16* __restrict__ A, const u16* __restrict__ BT,
    u16* __restrict__ C, int M, int K, int N)
{
    __shared__ __align__(16) u16 As[128 * 32];   // 8 KB, row-major [m][k]
    __shared__ __align__(16) u16 Bs[128 * 32];   // 8 KB, row-major [n][k]
    const int tid  = threadIdx.x;
    const int lane = tid & 63;
    const int wave = tid >> 6;
    const int wm = (wave >> 1) * 64, wn = (wave & 1) * 64;
    const int quad = lane >> 4, lr = lane & 15;
    const int m0 = blockIdx.y * 128;
    const int n0 = blockIdx.x * 128;

    // staging: chunk j (16B) covers row j>>2, k-col (j&3)*8. Thread stages j=tid, tid+256.
    const int r0 = tid >> 2, c0 = (tid & 3) * 8;           // r1 = r0+64, c1 = c0
    const u16* gA = A  + (size_t)(m0 + r0) * K + c0;
    const u16* gB = BT + (size_t)(n0 + r0) * K + c0;
    // wave-uniform LDS bases (u16 elems): round0 = wave*512, round1 = +2048
    u16* lA0 = As + wave * 512;  u16* lA1 = lA0 + 2048;
    u16* lB0 = Bs + wave * 512;  u16* lB1 = lB0 + 2048;
    const size_t rowStride = (size_t)64 * K;

    floatx4 acc[4][4] = {};

    for (int k0 = 0; k0 < K; k0 += 32) {
        async_copy16(lA0, gA + k0);
        async_copy16(lA1, gA + rowStride + k0);
        async_copy16(lB0, gB + k0);
        async_copy16(lB1, gB + rowStride + k0);
        __syncthreads();   // drains vmcnt: LDS tiles complete
        bf16x8 af[4], bfr[4];
#pragma unroll
        for (int i = 0; i < 4; ++i)
            af[i] = *(const bf16x8*)(As + (wm + i * 16 + lr) * 32 + quad * 8);
#pragma unroll
        for (int j = 0; j < 4; ++j)
            bfr[j] = *(const bf16x8*)(Bs + (wn + j * 16 + lr) * 32 + quad * 8);
#pragma unroll
        for (int i = 0; i < 4; ++i)
#pragma unroll
            for (int j = 0; j < 4; ++j)
                acc[i][j] = __builtin_amdgcn_mfma_f32_16x16x32_bf16(af[i], bfr[j], acc[i][j], 0, 0, 0);
        __syncthreads();   // frags consumed before next overwrite
    }
    // Epilogue: C/D layout col = lane&15, row = quad*4 + reg
#pragma unroll
    for (int i = 0; i < 4; ++i) {
        int rb = m0 + wm + i * 16 + quad * 4;
#pragma unroll
        for (int j = 0; j < 4; ++j) {
            int col = n0 + wn + j * 16 + lr;
#pragma unroll
            for (int rg = 0; rg < 4; ++rg)
                C[(size_t)(rb + rg) * N + col] = f32_to_bf16(acc[i][j][rg]);
        }
    }
}

// ---------------------------------------------------------------------------
// s[row] = mask ? sum_a tanh(R[row,a] + shift[row/shiftDiv, a]) * wv[a] : -1e30
// One wave per row; R is bf16 [rows,1024].
// ---------------------------------------------------------------------------
__global__ __launch_bounds__(256) void tanh_dot_kernel(
    const u16* __restrict__ R, const float* __restrict__ shift,
    const float* __restrict__ wv, const float* __restrict__ mask,
    float* __restrict__ out, int shiftDiv)
{
    const int row  = blockIdx.x * 4 + (threadIdx.x >> 6);
    const int lane = threadIdx.x & 63;
    const u16* rp   = R + (size_t)row * 1024;
    const float* sp = shift + (size_t)(row / shiftDiv) * 1024;
    float acc = 0.f;
#pragma unroll
    for (int p = 0; p < 2; ++p) {
        const int a0 = (p * 64 + lane) * 8;
        uint4  rv = *(const uint4*)(rp + a0);
        float4 s0 = *(const float4*)(sp + a0);
        float4 s1 = *(const float4*)(sp + a0 + 4);
        float4 w0 = *(const float4*)(wv + a0);
        float4 w1 = *(const float4*)(wv + a0 + 4);
        acc += fast_tanh(bf16_lo(rv.x) + s0.x) * w0.x;
        acc += fast_tanh(bf16_hi(rv.x) + s0.y) * w0.y;
        acc += fast_tanh(bf16_lo(rv.y) + s0.z) * w0.z;
        acc += fast_tanh(bf16_hi(rv.y) + s0.w) * w0.w;
        acc += fast_tanh(bf16_lo(rv.z) + s1.x) * w1.x;
        acc += fast_tanh(bf16_hi(rv.z) + s1.y) * w1.y;
        acc += fast_tanh(bf16_lo(rv.w) + s1.z) * w1.z;
        acc += fast_tanh(bf16_hi(rv.w) + s1.w) * w1.w;
    }
#pragma unroll
    for (int off = 32; off > 0; off >>= 1)
        acc += __shfl_down(acc, off, 64);
    if (lane == 0)
        out[row] = (mask[row] > 0.f) ? acc : -1e30f;
}

// ---------------------------------------------------------------------------
// Question pool: softmax over TQ=64 then hidden[b,h] = sum_t alpha[t]*q[b,t,h]
// ---------------------------------------------------------------------------
__global__ __launch_bounds__(256) void pool_q_kernel(
    const float* __restrict__ s, const float* __restrict__ seq, float* __restrict__ hidden)
{
    const int b = blockIdx.x, tid = threadIdx.x;
    __shared__ float alpha[64];
    if (tid < 64) {
        float v = s[b * 64 + tid];
        float m = v;
#pragma unroll
        for (int off = 32; off > 0; off >>= 1) m = fmaxf(m, __shfl_xor(m, off, 64));
        float e = __expf(v - m);
        float sum = e;
#pragma unroll
        for (int off = 32; off > 0; off >>= 1) sum += __shfl_xor(sum, off, 64);
        alpha[tid] = e * __builtin_amdgcn_rcpf(sum);
    }
    __syncthreads();
    float acc[4] = {0.f, 0.f, 0.f, 0.f};
    const float* base = seq + (size_t)b * 64 * 1024;
#pragma unroll 4
    for (int t = 0; t < 64; ++t) {
        const float a = alpha[t];
#pragma unroll
        for (int j = 0; j < 4; ++j)
            acc[j] += a * base[(size_t)t * 1024 + tid + j * 256];
    }
#pragma unroll
    for (int j = 0; j < 4; ++j) hidden[b * 1024 + tid + j * 256] = acc[j];
}

// ---------------------------------------------------------------------------
// Passage pool: softmax over TP=1024, pooled[b,h] = sum_t alpha[t]*p[b,t,h]
// grid (64 batches, 4 col-chunks of 256). Softmax recomputed per chunk.
// ---------------------------------------------------------------------------
__global__ __launch_bounds__(256) void pool_p_kernel(
    const float* __restrict__ s, const float* __restrict__ seq, float* __restrict__ pooled)
{
    const int b = blockIdx.x, tid = threadIdx.x;
    const int col = blockIdx.y * 256 + tid;
    const int lane = tid & 63, wid = tid >> 6;
    __shared__ float alpha[1024];
    __shared__ float redm[4], reds[4];
    const float* sr = s + b * 1024;
    float v[4];
    float m = -3.4e38f;
#pragma unroll
    for (int j = 0; j < 4; ++j) { v[j] = sr[tid + j * 256]; m = fmaxf(m, v[j]); }
#pragma unroll
    for (int off = 32; off > 0; off >>= 1) m = fmaxf(m, __shfl_xor(m, off, 64));
    if (lane == 0) redm[wid] = m;
    __syncthreads();
    m = fmaxf(fmaxf(redm[0], redm[1]), fmaxf(redm[2], redm[3]));
    float sum = 0.f;
#pragma unroll
    for (int j = 0; j < 4; ++j) { float e = __expf(v[j] - m); alpha[tid + j * 256] = e; sum += e; }
#pragma unroll
    for (int off = 32; off > 0; off >>= 1) sum += __shfl_xor(sum, off, 64);
    if (lane == 0) reds[wid] = sum;
    __syncthreads();
    const float rs = __builtin_amdgcn_rcpf(reds[0] + reds[1] + reds[2] + reds[3]);
    float acc = 0.f;
    const float* base = seq + (size_t)b * (1024 * 1024) + col;
#pragma unroll 8
    for (int t = 0; t < 1024; ++t)
        acc += alpha[t] * base[(size_t)t * 1024];
    pooled[b * 1024 + col] = acc * rs;
}

// ---------------------------------------------------------------------------
// Small fp32 GEMM: out[64,N] = X[64,K] @ B  (B is [N,K] if BT else [K,N]).
// 64x64 tile, BK=16, 4x4 micro-tile. blockIdx.y picks operand set.
// If SPLIT: blockIdx.z splits K into 4 chunks, atomicAdd epilogue (out must be 0).
// ---------------------------------------------------------------------------
template <bool BT, bool SPLIT>
__global__ __launch_bounds__(256) void small_gemm_kernel(
    const float* __restrict__ X0, const float* __restrict__ X1,
    const float* __restrict__ B0, const float* __restrict__ B1,
    float* __restrict__ out0, float* __restrict__ out1, int K, int N)
{
    const float* X  = blockIdx.y ? X1 : X0;
    const float* Bm = blockIdx.y ? B1 : B0;
    float* out      = blockIdx.y ? out1 : out0;
    const int n0 = blockIdx.x * 64;
    const int kBeg = SPLIT ? (int)blockIdx.z * (K >> 2) : 0;
    const int kEnd = SPLIT ? kBeg + (K >> 2) : K;
    const int tid = threadIdx.x, tx = tid & 15, ty = tid >> 4;
    __shared__ float Xs[64][17];
    __shared__ float Bs[64][17];
    float acc[4][4] = {};
    for (int kc = kBeg; kc < kEnd; kc += 16) {
        {
            int e = tid * 4, row = e >> 4, kk = e & 15;
            float4 v = *(const float4*)(X + (size_t)row * K + kc + kk);
            Xs[row][kk] = v.x; Xs[row][kk + 1] = v.y; Xs[row][kk + 2] = v.z; Xs[row][kk + 3] = v.w;
        }
        if (BT) {
            int e = tid * 4, n = e >> 4, kk = e & 15;
            float4 v = *(const float4*)(Bm + (size_t)(n0 + n) * K + kc + kk);
            Bs[n][kk] = v.x; Bs[n][kk + 1] = v.y; Bs[n][kk + 2] = v.z; Bs[n][kk + 3] = v.w;
        } else {
            int c = tid & 63, kb = tid >> 6;
#pragma unroll
            for (int u = 0; u < 4; ++u) {
                int k = kb + u * 4;
                Bs[c][k] = Bm[(size_t)(kc + k) * N + n0 + c];
            }
        }
        __syncthreads();
#pragma unroll
        for (int k = 0; k < 16; ++k) {
            float xr[4], br[4];
#pragma unroll
            for (int bi = 0; bi < 4; ++bi) xr[bi] = Xs[ty * 4 + bi][k];
#pragma unroll
            for (int ni = 0; ni < 4; ++ni) br[ni] = Bs[tx * 4 + ni][k];
#pragma unroll
            for (int bi = 0; bi < 4; ++bi)
#pragma unroll
                for (int ni = 0; ni < 4; ++ni)
                    acc[bi][ni] += xr[bi] * br[ni];
        }
        __syncthreads();
    }
#pragma unroll
    for (int bi = 0; bi < 4; ++bi)
#pragma unroll
        for (int ni = 0; ni < 4; ++ni) {
            float* p = out + (size_t)(ty * 4 + bi) * N + n0 + tx * 4 + ni;
            if (SPLIT) atomicAdd(p, acc[bi][ni]);
            else       *p = acc[bi][ni];
        }
}

// ---------------------------------------------------------------------------
// GRU cell combine (torch.nn.GRUCell math), biases applied here.
// ---------------------------------------------------------------------------
__global__ __launch_bounds__(256) void gru_combine_kernel(
    const float* __restrict__ gi, const float* __restrict__ gh,
    const float* __restrict__ bih, const float* __restrict__ bhh,
    const float* __restrict__ h, float* __restrict__ out)
{
    const int idx = blockIdx.x * 256 + threadIdx.x;   // 0..65535
    const int b = idx >> 10, j = idx & 1023;
    const float* gib = gi + (size_t)b * 3072;
    const float* ghb = gh + (size_t)b * 3072;
    float ir = gib[j] + bih[j],                hr = ghb[j] + bhh[j];
    float iz = gib[1024 + j] + bih[1024 + j],  hz = ghb[1024 + j] + bhh[1024 + j];
    float in_ = gib[2048 + j] + bih[2048 + j], hn = ghb[2048 + j] + bhh[2048 + j];
    float r = fast_sigmoid(ir + hr);
    float z = fast_sigmoid(iz + hz);
    float n = fast_tanh(in_ + r * hn);
    out[idx] = (1.f - z) * n + z * h[idx];
}

// ---------------------------------------------------------------------------
extern "C" void kernel_launch(void* const* d_in, const int* in_sizes, int n_in,
                              void* d_out, int out_size, void* d_ws, size_t ws_size,
                              hipStream_t stream)
{
    const float* question      = (const float*)d_in[0];   // [64,64,1024]
    const float* question_mask = (const float*)d_in[1];   // [64,64]
    const float* passage       = (const float*)d_in[2];   // [64,1024,1024]
    const float* passage_mask  = (const float*)d_in[3];   // [64,1024]
    const float* V_q  = (const float*)d_in[4];            // [1024]
    const float* Wk_q = (const float*)d_in[5];            // [1024,1024]
    const float* Wq_q = (const float*)d_in[6];
    const float* w_q  = (const float*)d_in[7];
    const float* Wk_p = (const float*)d_in[8];
    const float* Wq_p = (const float*)d_in[9];
    const float* w_p  = (const float*)d_in[10];
    const float* W_ih = (const float*)d_in[11];           // [3072,1024]
    const float* W_hh = (const float*)d_in[12];
    const float* b_ih = (const float*)d_in[13];
    const float* b_hh = (const float*)d_in[14];

    char* ws = (char*)d_ws;
    auto alloc = [&](size_t bytes) { char* p = ws; ws += (bytes + 255) & ~(size_t)255; return p; };
    u16* WkQT  = (u16*)alloc((size_t)1024 * 1024 * 2);    // Wk_q^T bf16 [A,K]
    u16* WkPT  = (u16*)alloc((size_t)1024 * 1024 * 2);    // Wk_p^T bf16 [A,K]
    u16* pbf   = (u16*)alloc((size_t)65536 * 1024 * 2);   // passage bf16 (128 MB)
    u16* qbf   = (u16*)alloc((size_t)4096 * 1024 * 2);    // question bf16
    u16* qWk   = (u16*)alloc((size_t)4096 * 1024 * 2);    // question@Wk_q bf16
    u16* pWk   = (u16*)alloc((size_t)65536 * 1024 * 2);   // passage@Wk_p bf16 (128 MB)
    float* vWq    = (float*)alloc(1024 * 4);
    float* s_q    = (float*)alloc(4096 * 4);
    float* hidden = (float*)alloc(65536 * 4);
    float* hWq    = (float*)alloc(65536 * 4);
    float* pooled = (float*)alloc(65536 * 4);
    float* gi     = (float*)alloc((size_t)64 * 3072 * 4);
    float* gh     = (float*)alloc((size_t)64 * 3072 * 4);
    float* gout   = (float*)alloc(65536 * 4);
    float* oWq    = (float*)alloc(65536 * 4);

    float* ans_begin = (float*)d_out;          // [64,1024]
    float* ans_end   = ans_begin + 65536;      // [64,1024]

    // zero-init accumulation targets (atomicAdd consumers)
    hipMemsetAsync(vWq, 0, 1024 * 4, stream);
    hipMemsetAsync(hWq, 0, 65536 * 4, stream);
    hipMemsetAsync(oWq, 0, 65536 * 4, stream);

    // bulk fp32->bf16 conversions + weight transposes
    conv_bf16_kernel<<<dim3(32768), 256, 0, stream>>>(passage, pbf);
    conv_bf16_kernel<<<dim3(2048), 256, 0, stream>>>(question, qbf);
    transpose_bf16_kernel<<<dim3(32, 32), 256, 0, stream>>>(Wk_q, WkQT, 1024, 1024);
    transpose_bf16_kernel<<<dim3(32, 32), 256, 0, stream>>>(Wk_p, WkPT, 1024, 1024);

    // big GEMM (dominant): pWk = passage @ Wk_p  (bf16 out)
    gemm_bf16_kernel<<<dim3(8, 512), 256, 0, stream>>>(pbf, WkPT, pWk, 65536, 1024, 1024);

    // question path
    gemm_bf16_kernel<<<dim3(8, 32), 256, 0, stream>>>(qbf, WkQT, qWk, 4096, 1024, 1024);
    vq_proj_kernel<<<dim3(4, 8), 256, 0, stream>>>(V_q, Wq_q, vWq);
    tanh_dot_kernel<<<dim3(1024), 256, 0, stream>>>(qWk, vWq, w_q, question_mask, s_q, 4096);
    pool_q_kernel<<<dim3(64), 256, 0, stream>>>(s_q, question, hidden);

    // begin logits
    small_gemm_kernel<false, true><<<dim3(16, 1, 4), 256, 0, stream>>>(
        hidden, hidden, Wq_p, Wq_p, hWq, hWq, 1024, 1024);
    tanh_dot_kernel<<<dim3(16384), 256, 0, stream>>>(pWk, hWq, w_p, passage_mask, ans_begin, 1024);

    // passage pool + GRU step
    pool_p_kernel<<<dim3(64, 4), 256, 0, stream>>>(ans_begin, passage, pooled);
    small_gemm_kernel<true, false><<<dim3(48, 2), 256, 0, stream>>>(
        pooled, hidden, W_ih, W_hh, gi, gh, 1024, 3072);
    gru_combine_kernel<<<dim3(256), 256, 0, stream>>>(gi, gh, b_ih, b_hh, hidden, gout);

    // end logits
    small_gemm_kernel<false, true><<<dim3(16, 1, 4), 256, 0, stream>>>(
        gout, gout, Wq_p, Wq_p, oWq, oWq, 1024, 1024);
    tanh_dot_kernel<<<dim3(16384), 256, 0, stream>>>(pWk, oWq, w_p, passage_mask, ans_end, 1024);
}

// Round 3
// 911.542 us; speedup vs baseline: 1.3021x; 1.0869x over previous
//
#include <hip/hip_runtime.h>
#include <cstdint>
#include <cstddef>

// Problem constants: B=64, TQ=64, TP=1024, H=A=1024
typedef unsigned short u16;
typedef __bf16 bf16x8 __attribute__((ext_vector_type(8)));
typedef float floatx4 __attribute__((ext_vector_type(4)));

__device__ __forceinline__ u16 f32_to_bf16(float f) {
    unsigned u = __builtin_bit_cast(unsigned, f);
    u += 0x7fffu + ((u >> 16) & 1u);   // round-to-nearest-even
    return (u16)(u >> 16);
}
__device__ __forceinline__ unsigned pack_bf16x2(float lo, float hi) {
    return (unsigned)f32_to_bf16(lo) | ((unsigned)f32_to_bf16(hi) << 16);
}
__device__ __forceinline__ float bf16_lo(unsigned u) {
    return __builtin_bit_cast(float, u << 16);
}
__device__ __forceinline__ float bf16_hi(unsigned u) {
    return __builtin_bit_cast(float, u & 0xffff0000u);
}
__device__ __forceinline__ float bf16f(u16 v) {
    return __builtin_bit_cast(float, (unsigned)v << 16);
}
__device__ __forceinline__ float fast_tanh(float x) {
    float e = __expf(2.0f * x);
    return 1.0f - 2.0f * __builtin_amdgcn_rcpf(e + 1.0f);
}
__device__ __forceinline__ float fast_sigmoid(float x) {
    return __builtin_amdgcn_rcpf(1.0f + __expf(-x));
}
// async global->LDS, 16 B per lane. LDS dest is wave-uniform base + lane*16.
__device__ __forceinline__ void async_copy16(void* lds, const void* g) {
    __builtin_amdgcn_global_load_lds((const __attribute__((address_space(1))) void*)g,
                                     (__attribute__((address_space(3))) void*)lds,
                                     16, 0, 0);
}

// ---------------------------------------------------------------------------
// fp32 -> bf16 bulk convert. Each thread: 8 floats -> one 16B store.
// ---------------------------------------------------------------------------
__global__ __launch_bounds__(256) void conv_bf16_kernel(
    const float* __restrict__ in, u16* __restrict__ out)
{
    const size_t i = ((size_t)blockIdx.x * 256 + threadIdx.x) * 8;
    float4 a = *(const float4*)(in + i);
    float4 b = *(const float4*)(in + i + 4);
    uint4 o;
    o.x = pack_bf16x2(a.x, a.y);
    o.y = pack_bf16x2(a.z, a.w);
    o.z = pack_bf16x2(b.x, b.y);
    o.w = pack_bf16x2(b.z, b.w);
    *(uint4*)(out + i) = o;
}

// ---------------------------------------------------------------------------
// Transpose+convert: W fp32 [K,N] -> WT bf16 [N,K]
// ---------------------------------------------------------------------------
__global__ __launch_bounds__(256) void transpose_bf16_kernel(
    const float* __restrict__ W, u16* __restrict__ WT, int K, int N)
{
    __shared__ float tile[32][33];
    const int k0 = blockIdx.y * 32, n0 = blockIdx.x * 32;
    const int tid = threadIdx.x;
#pragma unroll
    for (int i = 0; i < 4; ++i) {
        int e = tid + i * 256, rr = e >> 5, cc = e & 31;
        tile[rr][cc] = W[(size_t)(k0 + rr) * N + (n0 + cc)];
    }
    __syncthreads();
#pragma unroll
    for (int i = 0; i < 4; ++i) {
        int e = tid + i * 256, rr = e >> 5, cc = e & 31;
        WT[(size_t)(n0 + rr) * K + (k0 + cc)] = f32_to_bf16(tile[cc][rr]);
    }
}

// ---------------------------------------------------------------------------
// vWq[a] += sum_{h in chunk} V_q[h] * Wq_q[h,a].  grid (4, 8), atomicAdd.
// ---------------------------------------------------------------------------
__global__ __launch_bounds__(256) void vq_proj_kernel(
    const float* __restrict__ Vq, const float* __restrict__ Wq, float* __restrict__ out)
{
    const int a = blockIdx.x * 256 + threadIdx.x;
    const int h0 = blockIdx.y * 128;
    float acc = 0.f;
#pragma unroll 8
    for (int h = h0; h < h0 + 128; ++h)
        acc += Vq[h] * Wq[(size_t)h * 1024 + a];
    atomicAdd(&out[a], acc);
}

// ---------------------------------------------------------------------------
// m97-structure GEMM: C[M,N] bf16 = A bf16 [M,K] @ (BT bf16 [N,K])^T
// 128x128 tile, BK=32, 4 waves (2x2), 16x16x32 bf16 MFMA, 4x4 frags/wave.
// Staging via global_load_lds dwordx4 (16B/lane).
// FUSE: 1-D grid with XCD-aware swizzle (xcd=blk&7; 8 consecutive blocks on
// one XCD share an m-stripe -> A-stripe fetched from HBM once, L2-resident);
// epilogue also accumulates begin-logit partials:
//   sOut[row] += sum_col tanh(acc + shift[b,col]) * wv[col]   (atomicAdd)
// ---------------------------------------------------------------------------
template <bool FUSE>
__global__ __launch_bounds__(256) void gemm_bf16_kernel(
    const u16* __restrict__ A, const u16* __restrict__ BT,
    u16* __restrict__ C, const float* __restrict__ shift,
    const float* __restrict__ wv, float* __restrict__ sOut, int K, int N)
{
    __shared__ __align__(16) u16 As[128 * 32];   // 8 KB, row-major [m][k]
    __shared__ __align__(16) u16 Bs[128 * 32];   // 8 KB, row-major [n][k]
    const int tid  = threadIdx.x;
    const int lane = tid & 63;
    const int wave = tid >> 6;
    const int wm = (wave >> 1) * 64, wn = (wave & 1) * 64;
    const int quad = lane >> 4, lr = lane & 15;
    int m0, n0;
    if (FUSE) {
        const int blk = blockIdx.x;
        const int xcd = blk & 7, s = blk >> 3;
        const int tx = s & 7, ty = ((s >> 3) << 3) | xcd;
        m0 = ty * 128; n0 = tx * 128;
    } else {
        m0 = blockIdx.y * 128; n0 = blockIdx.x * 128;
    }

    const int r0 = tid >> 2, c0 = (tid & 3) * 8;
    const u16* gA = A  + (size_t)(m0 + r0) * K + c0;
    const u16* gB = BT + (size_t)(n0 + r0) * K + c0;
    u16* lA0 = As + wave * 512;  u16* lA1 = lA0 + 2048;
    u16* lB0 = Bs + wave * 512;  u16* lB1 = lB0 + 2048;
    const size_t rowStride = (size_t)64 * K;

    floatx4 acc[4][4] = {};

    for (int k0 = 0; k0 < K; k0 += 32) {
        async_copy16(lA0, gA + k0);
        async_copy16(lA1, gA + rowStride + k0);
        async_copy16(lB0, gB + k0);
        async_copy16(lB1, gB + rowStride + k0);
        __syncthreads();
        bf16x8 af[4], bfr[4];
#pragma unroll
        for (int i = 0; i < 4; ++i)
            af[i] = *(const bf16x8*)(As + (wm + i * 16 + lr) * 32 + quad * 8);
#pragma unroll
        for (int j = 0; j < 4; ++j)
            bfr[j] = *(const bf16x8*)(Bs + (wn + j * 16 + lr) * 32 + quad * 8);
#pragma unroll
        for (int i = 0; i < 4; ++i)
#pragma unroll
            for (int j = 0; j < 4; ++j)
                acc[i][j] = __builtin_amdgcn_mfma_f32_16x16x32_bf16(af[i], bfr[j], acc[i][j], 0, 0, 0);
        __syncthreads();
    }
    // Epilogue: C/D layout col = lane&15, row = quad*4 + reg
#pragma unroll
    for (int i = 0; i < 4; ++i) {
        int rb = m0 + wm + i * 16 + quad * 4;
#pragma unroll
        for (int j = 0; j < 4; ++j) {
            int col = n0 + wn + j * 16 + lr;
#pragma unroll
            for (int rg = 0; rg < 4; ++rg)
                C[(size_t)(rb + rg) * N + col] = f32_to_bf16(acc[i][j][rg]);
        }
    }
    if (FUSE) {
        const int b = m0 >> 10;          // 128-row tile never crosses a batch
        float hq[4], wp[4];
#pragma unroll
        for (int j = 0; j < 4; ++j) {
            int col = n0 + wn + j * 16 + lr;
            hq[j] = shift[b * 1024 + col];
            wp[j] = wv[col];
        }
#pragma unroll
        for (int i = 0; i < 4; ++i) {
#pragma unroll
            for (int rg = 0; rg < 4; ++rg) {
                float t = 0.f;
#pragma unroll
                for (int j = 0; j < 4; ++j)
                    t += fast_tanh(acc[i][j][rg] + hq[j]) * wp[j];
                // reduce over the 16 lanes of this quad (cols)
#pragma unroll
                for (int off = 1; off < 16; off <<= 1)
                    t += __shfl_xor(t, off, 64);
                if (lr == 0)
                    atomicAdd(&sOut[m0 + wm + i * 16 + quad * 4 + rg], t);
            }
        }
    }
}

// ---------------------------------------------------------------------------
// s[row] = mask ? sum_a tanh(R[row,a] + shift[row/shiftDiv, a]) * wv[a] : -1e30
// One wave per row; R is bf16 [rows,1024].
// ---------------------------------------------------------------------------
__global__ __launch_bounds__(256) void tanh_dot_kernel(
    const u16* __restrict__ R, const float* __restrict__ shift,
    const float* __restrict__ wv, const float* __restrict__ mask,
    float* __restrict__ out, int shiftDiv)
{
    const int row  = blockIdx.x * 4 + (threadIdx.x >> 6);
    const int lane = threadIdx.x & 63;
    const u16* rp   = R + (size_t)row * 1024;
    const float* sp = shift + (size_t)(row / shiftDiv) * 1024;
    float acc = 0.f;
#pragma unroll
    for (int p = 0; p < 2; ++p) {
        const int a0 = (p * 64 + lane) * 8;
        uint4  rv = *(const uint4*)(rp + a0);
        float4 s0 = *(const float4*)(sp + a0);
        float4 s1 = *(const float4*)(sp + a0 + 4);
        float4 w0 = *(const float4*)(wv + a0);
        float4 w1 = *(const float4*)(wv + a0 + 4);
        acc += fast_tanh(bf16_lo(rv.x) + s0.x) * w0.x;
        acc += fast_tanh(bf16_hi(rv.x) + s0.y) * w0.y;
        acc += fast_tanh(bf16_lo(rv.y) + s0.z) * w0.z;
        acc += fast_tanh(bf16_hi(rv.y) + s0.w) * w0.w;
        acc += fast_tanh(bf16_lo(rv.z) + s1.x) * w1.x;
        acc += fast_tanh(bf16_hi(rv.z) + s1.y) * w1.y;
        acc += fast_tanh(bf16_lo(rv.w) + s1.z) * w1.z;
        acc += fast_tanh(bf16_hi(rv.w) + s1.w) * w1.w;
    }
#pragma unroll
    for (int off = 32; off > 0; off >>= 1)
        acc += __shfl_down(acc, off, 64);
    if (lane == 0)
        out[row] = (mask[row] > 0.f) ? acc : -1e30f;
}

// ---------------------------------------------------------------------------
// out[idx] = mask[idx] > 0 ? sIn[idx] : -1e30
// ---------------------------------------------------------------------------
__global__ __launch_bounds__(256) void mask_kernel(
    const float* __restrict__ sIn, const float* __restrict__ mask, float* __restrict__ out)
{
    const int idx = blockIdx.x * 256 + threadIdx.x;
    out[idx] = (mask[idx] > 0.f) ? sIn[idx] : -1e30f;
}

// ---------------------------------------------------------------------------
// Question pool: softmax over TQ=64 then hidden[b,h] = sum_t alpha[t]*q[b,t,h]
// ---------------------------------------------------------------------------
__global__ __launch_bounds__(256) void pool_q_kernel(
    const float* __restrict__ s, const float* __restrict__ seq, float* __restrict__ hidden)
{
    const int b = blockIdx.x, tid = threadIdx.x;
    __shared__ float alpha[64];
    if (tid < 64) {
        float v = s[b * 64 + tid];
        float m = v;
#pragma unroll
        for (int off = 32; off > 0; off >>= 1) m = fmaxf(m, __shfl_xor(m, off, 64));
        float e = __expf(v - m);
        float sum = e;
#pragma unroll
        for (int off = 32; off > 0; off >>= 1) sum += __shfl_xor(sum, off, 64);
        alpha[tid] = e * __builtin_amdgcn_rcpf(sum);
    }
    __syncthreads();
    float acc[4] = {0.f, 0.f, 0.f, 0.f};
    const float* base = seq + (size_t)b * 64 * 1024;
#pragma unroll 4
    for (int t = 0; t < 64; ++t) {
        const float a = alpha[t];
#pragma unroll
        for (int j = 0; j < 4; ++j)
            acc[j] += a * base[(size_t)t * 1024 + tid + j * 256];
    }
#pragma unroll
    for (int j = 0; j < 4; ++j) hidden[b * 1024 + tid + j * 256] = acc[j];
}

// ---------------------------------------------------------------------------
// Passage pool over bf16 passage copy, t-split.
// grid (64 b, 4 col-chunks of 256, 4 t-chunks of 256); atomicAdd into pooled.
// ---------------------------------------------------------------------------
__global__ __launch_bounds__(256) void pool_p_kernel(
    const float* __restrict__ s, const u16* __restrict__ seq, float* __restrict__ pooled)
{
    const int b = blockIdx.x, tid = threadIdx.x;
    const int col = blockIdx.y * 256 + tid;
    const int t0 = blockIdx.z * 256;
    const int lane = tid & 63, wid = tid >> 6;
    __shared__ float alpha[1024];
    __shared__ float redm[4], reds[4];
    const float* sr = s + b * 1024;
    float v[4];
    float m = -3.4e38f;
#pragma unroll
    for (int j = 0; j < 4; ++j) { v[j] = sr[tid + j * 256]; m = fmaxf(m, v[j]); }
#pragma unroll
    for (int off = 32; off > 0; off >>= 1) m = fmaxf(m, __shfl_xor(m, off, 64));
    if (lane == 0) redm[wid] = m;
    __syncthreads();
    m = fmaxf(fmaxf(redm[0], redm[1]), fmaxf(redm[2], redm[3]));
    float sum = 0.f;
#pragma unroll
    for (int j = 0; j < 4; ++j) { float e = __expf(v[j] - m); alpha[tid + j * 256] = e; sum += e; }
#pragma unroll
    for (int off = 32; off > 0; off >>= 1) sum += __shfl_xor(sum, off, 64);
    if (lane == 0) reds[wid] = sum;
    __syncthreads();
    const float rs = __builtin_amdgcn_rcpf(reds[0] + reds[1] + reds[2] + reds[3]);
    float acc = 0.f;
    const u16* base = seq + (size_t)b * (1024 * 1024) + (size_t)t0 * 1024 + col;
#pragma unroll 8
    for (int t = 0; t < 256; ++t)
        acc += alpha[t0 + t] * bf16f(base[(size_t)t * 1024]);
    atomicAdd(&pooled[b * 1024 + col], acc * rs);
}

// ---------------------------------------------------------------------------
// Small fp32 GEMM: out[64,N] = X[64,K] @ B  (B is [N,K] if BT else [K,N]).
// 64x64 tile, BK=16, 4x4 micro-tile. blockIdx.y picks operand set.
// If SPLIT: blockIdx.z splits K into 4 chunks, atomicAdd epilogue (out must be 0).
// ---------------------------------------------------------------------------
template <bool BT, bool SPLIT>
__global__ __launch_bounds__(256) void small_gemm_kernel(
    const float* __restrict__ X0, const float* __restrict__ X1,
    const float* __restrict__ B0, const float* __restrict__ B1,
    float* __restrict__ out0, float* __restrict__ out1, int K, int N)
{
    const float* X  = blockIdx.y ? X1 : X0;
    const float* Bm = blockIdx.y ? B1 : B0;
    float* out      = blockIdx.y ? out1 : out0;
    const int n0 = blockIdx.x * 64;
    const int kBeg = SPLIT ? (int)blockIdx.z * (K >> 2) : 0;
    const int kEnd = SPLIT ? kBeg + (K >> 2) : K;
    const int tid = threadIdx.x, tx = tid & 15, ty = tid >> 4;
    __shared__ float Xs[64][17];
    __shared__ float Bs[64][17];
    float acc[4][4] = {};
    for (int kc = kBeg; kc < kEnd; kc += 16) {
        {
            int e = tid * 4, row = e >> 4, kk = e & 15;
            float4 v = *(const float4*)(X + (size_t)row * K + kc + kk);
            Xs[row][kk] = v.x; Xs[row][kk + 1] = v.y; Xs[row][kk + 2] = v.z; Xs[row][kk + 3] = v.w;
        }
        if (BT) {
            int e = tid * 4, n = e >> 4, kk = e & 15;
            float4 v = *(const float4*)(Bm + (size_t)(n0 + n) * K + kc + kk);
            Bs[n][kk] = v.x; Bs[n][kk + 1] = v.y; Bs[n][kk + 2] = v.z; Bs[n][kk + 3] = v.w;
        } else {
            int c = tid & 63, kb = tid >> 6;
#pragma unroll
            for (int u = 0; u < 4; ++u) {
                int k = kb + u * 4;
                Bs[c][k] = Bm[(size_t)(kc + k) * N + n0 + c];
            }
        }
        __syncthreads();
#pragma unroll
        for (int k = 0; k < 16; ++k) {
            float xr[4], br[4];
#pragma unroll
            for (int bi = 0; bi < 4; ++bi) xr[bi] = Xs[ty * 4 + bi][k];
#pragma unroll
            for (int ni = 0; ni < 4; ++ni) br[ni] = Bs[tx * 4 + ni][k];
#pragma unroll
            for (int bi = 0; bi < 4; ++bi)
#pragma unroll
                for (int ni = 0; ni < 4; ++ni)
                    acc[bi][ni] += xr[bi] * br[ni];
        }
        __syncthreads();
    }
#pragma unroll
    for (int bi = 0; bi < 4; ++bi)
#pragma unroll
        for (int ni = 0; ni < 4; ++ni) {
            float* p = out + (size_t)(ty * 4 + bi) * N + n0 + tx * 4 + ni;
            if (SPLIT) atomicAdd(p, acc[bi][ni]);
            else       *p = acc[bi][ni];
        }
}

// ---------------------------------------------------------------------------
// GRU cell combine (torch.nn.GRUCell math), biases applied here.
// ---------------------------------------------------------------------------
__global__ __launch_bounds__(256) void gru_combine_kernel(
    const float* __restrict__ gi, const float* __restrict__ gh,
    const float* __restrict__ bih, const float* __restrict__ bhh,
    const float* __restrict__ h, float* __restrict__ out)
{
    const int idx = blockIdx.x * 256 + threadIdx.x;   // 0..65535
    const int b = idx >> 10, j = idx & 1023;
    const float* gib = gi + (size_t)b * 3072;
    const float* ghb = gh + (size_t)b * 3072;
    float ir = gib[j] + bih[j],                hr = ghb[j] + bhh[j];
    float iz = gib[1024 + j] + bih[1024 + j],  hz = ghb[1024 + j] + bhh[1024 + j];
    float in_ = gib[2048 + j] + bih[2048 + j], hn = ghb[2048 + j] + bhh[2048 + j];
    float r = fast_sigmoid(ir + hr);
    float z = fast_sigmoid(iz + hz);
    float n = fast_tanh(in_ + r * hn);
    out[idx] = (1.f - z) * n + z * h[idx];
}

// ---------------------------------------------------------------------------
extern "C" void kernel_launch(void* const* d_in, const int* in_sizes, int n_in,
                              void* d_out, int out_size, void* d_ws, size_t ws_size,
                              hipStream_t stream)
{
    const float* question      = (const float*)d_in[0];   // [64,64,1024]
    const float* question_mask = (const float*)d_in[1];   // [64,64]
    const float* passage       = (const float*)d_in[2];   // [64,1024,1024]
    const float* passage_mask  = (const float*)d_in[3];   // [64,1024]
    const float* V_q  = (const float*)d_in[4];            // [1024]
    const float* Wk_q = (const float*)d_in[5];            // [1024,1024]
    const float* Wq_q = (const float*)d_in[6];
    const float* w_q  = (const float*)d_in[7];
    const float* Wk_p = (const float*)d_in[8];
    const float* Wq_p = (const float*)d_in[9];
    const float* w_p  = (const float*)d_in[10];
    const float* W_ih = (const float*)d_in[11];           // [3072,1024]
    const float* W_hh = (const float*)d_in[12];
    const float* b_ih = (const float*)d_in[13];
    const float* b_hh = (const float*)d_in[14];

    char* ws = (char*)d_ws;
    auto alloc = [&](size_t bytes) { char* p = ws; ws += (bytes + 255) & ~(size_t)255; return p; };
    u16* WkQT  = (u16*)alloc((size_t)1024 * 1024 * 2);    // Wk_q^T bf16 [A,K]
    u16* WkPT  = (u16*)alloc((size_t)1024 * 1024 * 2);    // Wk_p^T bf16 [A,K]
    u16* pbf   = (u16*)alloc((size_t)65536 * 1024 * 2);   // passage bf16 (128 MB)
    u16* qbf   = (u16*)alloc((size_t)4096 * 1024 * 2);    // question bf16
    u16* qWk   = (u16*)alloc((size_t)4096 * 1024 * 2);    // question@Wk_q bf16
    u16* pWk   = (u16*)alloc((size_t)65536 * 1024 * 2);   // passage@Wk_p bf16 (128 MB)
    float* vWq    = (float*)alloc(1024 * 4);
    float* s_q    = (float*)alloc(4096 * 4);
    float* hidden = (float*)alloc(65536 * 4);
    float* hWq    = (float*)alloc(65536 * 4);
    float* sBegin = (float*)alloc(65536 * 4);             // raw begin logits (atomic)
    float* pooled = (float*)alloc(65536 * 4);
    float* gi     = (float*)alloc((size_t)64 * 3072 * 4);
    float* gh     = (float*)alloc((size_t)64 * 3072 * 4);
    float* gout   = (float*)alloc(65536 * 4);
    float* oWq    = (float*)alloc(65536 * 4);

    float* ans_begin = (float*)d_out;          // [64,1024]
    float* ans_end   = ans_begin + 65536;      // [64,1024]

    // zero-init accumulation targets (atomicAdd consumers)
    hipMemsetAsync(vWq, 0, 1024 * 4, stream);
    hipMemsetAsync(hWq, 0, 65536 * 4, stream);
    hipMemsetAsync(oWq, 0, 65536 * 4, stream);
    hipMemsetAsync(sBegin, 0, 65536 * 4, stream);
    hipMemsetAsync(pooled, 0, 65536 * 4, stream);

    // bulk fp32->bf16 conversions + weight transposes
    conv_bf16_kernel<<<dim3(32768), 256, 0, stream>>>(passage, pbf);
    conv_bf16_kernel<<<dim3(2048), 256, 0, stream>>>(question, qbf);
    transpose_bf16_kernel<<<dim3(32, 32), 256, 0, stream>>>(Wk_q, WkQT, 1024, 1024);
    transpose_bf16_kernel<<<dim3(32, 32), 256, 0, stream>>>(Wk_p, WkPT, 1024, 1024);

    // question path first (produces hWq for the fused big-GEMM epilogue)
    gemm_bf16_kernel<false><<<dim3(8, 32), 256, 0, stream>>>(
        qbf, WkQT, qWk, nullptr, nullptr, nullptr, 1024, 1024);
    vq_proj_kernel<<<dim3(4, 8), 256, 0, stream>>>(V_q, Wq_q, vWq);
    tanh_dot_kernel<<<dim3(1024), 256, 0, stream>>>(qWk, vWq, w_q, question_mask, s_q, 4096);
    pool_q_kernel<<<dim3(64), 256, 0, stream>>>(s_q, question, hidden);
    small_gemm_kernel<false, true><<<dim3(16, 1, 4), 256, 0, stream>>>(
        hidden, hidden, Wq_p, Wq_p, hWq, hWq, 1024, 1024);

    // big GEMM (dominant): pWk = passage @ Wk_p, fused begin-logit partials
    gemm_bf16_kernel<true><<<dim3(4096), 256, 0, stream>>>(
        pbf, WkPT, pWk, hWq, w_p, sBegin, 1024, 1024);
    mask_kernel<<<dim3(256), 256, 0, stream>>>(sBegin, passage_mask, ans_begin);

    // passage pool + GRU step
    pool_p_kernel<<<dim3(64, 4, 4), 256, 0, stream>>>(ans_begin, pbf, pooled);
    small_gemm_kernel<true, false><<<dim3(48, 2), 256, 0, stream>>>(
        pooled, hidden, W_ih, W_hh, gi, gh, 1024, 3072);
    gru_combine_kernel<<<dim3(256), 256, 0, stream>>>(gi, gh, b_ih, b_hh, hidden, gout);

    // end logits
    small_gemm_kernel<false, true><<<dim3(16, 1, 4), 256, 0, stream>>>(
        gout, gout, Wq_p, Wq_p, oWq, oWq, 1024, 1024);
    tanh_dot_kernel<<<dim3(16384), 256, 0, stream>>>(pWk, oWq, w_p, passage_mask, ans_end, 1024);
}